// Round 8
// baseline (165.379 us; speedup 1.0000x reference)
//
#include <hip/hip_runtime.h>
#include <hip/hip_bf16.h>

// GQA forward, round 7: V pre-transposed globally (vt[b,h][d][s]); flash stages
// both K and V tiles via global_load_lds DMA (no in-kernel transpose), 128-q
// blocks, 32 q/wave, double-buffered K/V, swapped QK^T, ones-MFMA row sums,
// cvt_pk packed P, defer-max, XCD remap.
// B=2, S=2048, HIDDEN=1024, 16 heads x 64 dim, RoPE over full hidden (half=512).
// ws (ushort elems): q(4M) k(4M) v(4M) ao(4M) xb(4M) wall(4M) vt(4M) = 56 MB.

constexpr int Bb  = 2;
constexpr int Ss  = 2048;
constexpr int Hh  = 1024;
constexpr int NHh = 16;
constexpr int Mm  = Bb * Ss;   // 4096 rows

typedef __attribute__((ext_vector_type(8))) unsigned short ushort8;
typedef __attribute__((ext_vector_type(4))) unsigned short ushort4_t;
typedef __attribute__((ext_vector_type(8))) short short8;
typedef __attribute__((ext_vector_type(4))) float f32x4;

__device__ __forceinline__ unsigned short f2bf(float f) {
    unsigned int u = __float_as_uint(f);
    u += 0x7fffu + ((u >> 16) & 1u);
    return (unsigned short)(u >> 16);
}
__device__ __forceinline__ float bf2f(unsigned short h) {
    return __uint_as_float(((unsigned int)h) << 16);
}
__device__ __forceinline__ void gload16(const void* g, void* l) {
    __builtin_amdgcn_global_load_lds(
        (const __attribute__((address_space(1))) unsigned int*)g,
        (__attribute__((address_space(3))) unsigned int*)l, 16, 0, 0);
}

// ---------------- fp32 -> bf16 convert (x, Wq|Wk|Wv|Wo into one block) ----------
__global__ __launch_bounds__(256) void convert_k(
    const float* __restrict__ x,
    const float* __restrict__ Wq, const float* __restrict__ Wk,
    const float* __restrict__ Wv, const float* __restrict__ Wo,
    unsigned short* __restrict__ xb, unsigned short* __restrict__ wall)
{
    size_t e = ((size_t)blockIdx.x * 256 + threadIdx.x) << 3;
    const float* s; unsigned short* d;
    if (e < (size_t)Mm * Hh) {
        s = x + e; d = xb + e;
    } else {
        size_t f = e - (size_t)Mm * Hh;
        int t = (int)(f >> 20);
        const float* w = (t == 0) ? Wq : (t == 1) ? Wk : (t == 2) ? Wv : Wo;
        s = w + (f & 1048575);
        d = wall + f;
    }
    float4 a = *(const float4*)s;
    float4 b = *(const float4*)(s + 4);
    ushort8 o;
    o[0] = f2bf(a.x); o[1] = f2bf(a.y); o[2] = f2bf(a.z); o[3] = f2bf(a.w);
    o[4] = f2bf(b.x); o[5] = f2bf(b.y); o[6] = f2bf(b.z); o[7] = f2bf(b.w);
    *(ushort8*)d = o;
}

// ---------------- bf16 MFMA GEMM core ---------------------------------------------
#define GEMM_BODY(ATYPE_PTR, WPTR, K0MAX)                                          \
    __shared__ unsigned short As[128 * 64];                                        \
    __shared__ unsigned short Bs[128 * 64];                                        \
    const int tid  = threadIdx.x;                                                  \
    const int lane = tid & 63;                                                     \
    const int w    = tid >> 6;                                                     \
    const int wr   = w >> 1, wc = w & 1;                                           \
    const int l16  = lane & 15, g = lane >> 4;                                     \
    const int R0   = blockIdx.x * 128;                                             \
    char* asb = (char*)As; char* bsb = (char*)Bs;                                  \
    f32x4 acc[4][4] = {};                                                          \
    for (int k0 = 0; k0 < K0MAX; k0 += 64) {                                       \
        _Pragma("unroll")                                                          \
        for (int it = 0; it < 4; ++it) {                                           \
            int sbase = w * 4096 + it * 1024;                                      \
            int boff  = sbase + lane * 16;                                         \
            int r     = boff >> 7;                                                 \
            int c     = (boff >> 4) & 7;                                           \
            int col   = k0 + ((c ^ (r & 7)) << 3);                                 \
            gload16(&ATYPE_PTR[(size_t)(R0 + r) * 1024 + col], asb + sbase);       \
            gload16(&WPTR[(size_t)(gn + r) * 1024 + col], bsb + sbase);            \
        }                                                                          \
        __syncthreads();                                                           \
        short8 bfrag[4][2];                                                        \
        _Pragma("unroll")                                                          \
        for (int u = 0; u < 4; ++u) {                                              \
            int row = wc * 64 + u * 16 + l16;                                      \
            _Pragma("unroll")                                                      \
            for (int s = 0; s < 2; ++s)                                            \
                bfrag[u][s] = *(const short8*)(bsb + row * 128 +                   \
                               ((s * 64 + g * 16) ^ ((row & 7) << 4)));            \
        }                                                                          \
        _Pragma("unroll")                                                          \
        for (int t = 0; t < 4; ++t) {                                              \
            int row = wr * 64 + t * 16 + l16;                                      \
            short8 af[2];                                                          \
            _Pragma("unroll")                                                      \
            for (int s = 0; s < 2; ++s)                                            \
                af[s] = *(const short8*)(asb + row * 128 +                         \
                         ((s * 64 + g * 16) ^ ((row & 7) << 4)));                  \
            _Pragma("unroll")                                                      \
            for (int u = 0; u < 4; ++u) {                                          \
                acc[t][u] = __builtin_amdgcn_mfma_f32_16x16x32_bf16(af[0], bfrag[u][0], acc[t][u], 0, 0, 0); \
                acc[t][u] = __builtin_amdgcn_mfma_f32_16x16x32_bf16(af[1], bfrag[u][1], acc[t][u], 0, 0, 0); \
            }                                                                      \
        }                                                                          \
        __syncthreads();                                                           \
    }

__global__ __launch_bounds__(256) void gemm_qkv_k(
    const unsigned short* __restrict__ xb, const unsigned short* __restrict__ wall,
    const float* __restrict__ bq, const float* __restrict__ bk, const float* __restrict__ bv,
    unsigned short* __restrict__ q, unsigned short* __restrict__ k2,
    unsigned short* __restrict__ v)
{
    const int gn = blockIdx.y * 128;
    GEMM_BODY(xb, wall, 1024)

    const int sel = gn >> 10;
    const int n0  = gn & 1023;
    const float* bias = (sel == 0) ? bq : (sel == 1) ? bk : bv;
    unsigned short* outp = (sel == 0) ? q : (sel == 1) ? k2 : v;
    // Pre-scale q by (1/8)*log2e: q feeds only QK^T; scale commutes with RoPE.
    const float qs = (sel == 0) ? 0.18033688011112042f : 1.0f;
    #pragma unroll
    for (int u = 0; u < 4; ++u) {
        int coll = wc * 64 + u * 16 + l16;
        float bb = bias[n0 + coll];
        #pragma unroll
        for (int t = 0; t < 4; ++t)
            #pragma unroll
            for (int rr = 0; rr < 4; ++rr) {
                int row = R0 + wr * 64 + t * 16 + g * 4 + rr;
                outp[(size_t)row * 1024 + n0 + coll] = f2bf((acc[t][u][rr] + bb) * qs);
            }
    }
}

__global__ __launch_bounds__(256) void gemm_out_k(
    const unsigned short* __restrict__ ao, const unsigned short* __restrict__ wo,
    const float* __restrict__ bo, float* __restrict__ out)
{
    const int gn = blockIdx.y * 128;
    GEMM_BODY(ao, wo, 1024)

    #pragma unroll
    for (int u = 0; u < 4; ++u) {
        int coll = wc * 64 + u * 16 + l16;
        float bb = bo[gn + coll];
        #pragma unroll
        for (int t = 0; t < 4; ++t)
            #pragma unroll
            for (int rr = 0; rr < 4; ++rr) {
                int row = R0 + wr * 64 + t * 16 + g * 4 + rr;
                out[(size_t)row * 1024 + gn + coll] = acc[t][u][rr] + bb;
            }
    }
}

// ---------------- RoPE on bf16 ----------------------------------------------------
__global__ __launch_bounds__(256) void rope_k(
    unsigned short* __restrict__ q, unsigned short* __restrict__ kk)
{
    int idx = blockIdx.x * 256 + threadIdx.x;
    int row = idx >> 7;
    int j4  = (idx & 127) << 2;
    int pos = row & (Ss - 1);
    size_t base = (size_t)row * 1024;

    ushort4_t qa = *(ushort4_t*)&q[base + j4];
    ushort4_t qb = *(ushort4_t*)&q[base + 512 + j4];
    ushort4_t ka = *(ushort4_t*)&kk[base + j4];
    ushort4_t kb = *(ushort4_t*)&kk[base + 512 + j4];

    #pragma unroll
    for (int t = 0; t < 4; ++t) {
        float jj = (float)(j4 + t);
        float inv = exp2f(jj * -0.0259525632621414f);  // 10000^(-j/512)
        float ang = (float)pos * inv;
        float sn, cs;
        __sincosf(ang, &sn, &cs);
        float a = bf2f(qa[t]), b = bf2f(qb[t]);
        qa[t] = f2bf(a * cs - b * sn);
        qb[t] = f2bf(b * cs + a * sn);
        float c = bf2f(ka[t]), d = bf2f(kb[t]);
        ka[t] = f2bf(c * cs - d * sn);
        kb[t] = f2bf(d * cs + c * sn);
    }
    *(ushort4_t*)&q[base + j4]        = qa;
    *(ushort4_t*)&q[base + 512 + j4]  = qb;
    *(ushort4_t*)&kk[base + j4]       = ka;
    *(ushort4_t*)&kk[base + 512 + j4] = kb;
}

// ---------------- V global transpose: v[b*S+s][h*64+d] -> vt[bh][d][s] -----------
__global__ __launch_bounds__(256) void transpose_v_k(
    const unsigned short* __restrict__ v, unsigned short* __restrict__ vt)
{
    __shared__ unsigned short Ld[64][72];   // 144B stride, 16B-aligned rows
    const int bh = blockIdx.y;              // 0..31  (bz*16 + h)
    const int s0 = blockIdx.x * 64;
    const int bz = bh >> 4, h = bh & 15;
    const int t  = threadIdx.x;
    const int r  = t >> 2;                  // 0..63
    const int c0 = (t & 3) * 16;

    const unsigned short* src = &v[(size_t)(bz * Ss + s0 + r) * 1024 + h * 64 + c0];
    *(ushort8*)&Ld[r][c0]     = *(const ushort8*)src;
    *(ushort8*)&Ld[r][c0 + 8] = *(const ushort8*)(src + 8);
    __syncthreads();

    unsigned short* dst = &vt[(size_t)bh * 64 * 2048 + (size_t)r * 2048 + s0 + c0];
    ushort8 o0, o1;
    #pragma unroll
    for (int j = 0; j < 8; ++j) { o0[j] = Ld[c0 + j][r]; o1[j] = Ld[c0 + 8 + j][r]; }
    *(ushort8*)dst       = o0;
    *(ushort8*)(dst + 8) = o1;
}

// ---------------- Flash attention: 128-q blocks, DMA-staged K and V --------------
__global__ __launch_bounds__(256, 3) void flash_k(
    const unsigned short* __restrict__ q, const unsigned short* __restrict__ k,
    const unsigned short* __restrict__ vt, const int* __restrict__ mask,
    unsigned short* __restrict__ ao)
{
    __shared__ unsigned short Ks[2][64 * 64];   // 16 KB, XOR-swizzled rows (key-major)
    __shared__ unsigned short Vt[2][64 * 64];   // 16 KB, XOR-swizzled rows (d-major)
    __shared__ unsigned short Pb[4][32 * 64];   // 16 KB, per-wave [q][key]

    // Bijective XCD remap: 512 blocks = 8 XCDs x (4 (h,bz) groups x 16 q-blocks).
    const int F   = blockIdx.x;
    const int xcd = F & 7, j = F >> 3;           // j: 0..63
    const int grp = xcd * 4 + (j >> 4);          // 0..31
    const int qb  = j & 15;
    const int h   = grp & 15;
    const int bz  = grp >> 4;

    const int tid  = threadIdx.x;
    const int lane = tid & 63;
    const int w    = tid >> 6;
    const int l16  = lane & 15;
    const int g    = lane >> 4;       // 0..3
    const int sw   = (lane & 7) << 4; // XOR key for rows with row&7 == lane&7

    const int qrowbase = bz * Ss + qb * 128 + w * 32;
    const size_t kbase  = (size_t)(bz * Ss) * 1024 + h * 64;           // k rows
    const size_t vtbase = (size_t)(bz * 16 + h) * 64 * 2048;           // vt rows

    // Q fragments (pre-scaled by (1/8)*log2e): [t][s], lane l16 = query
    short8 qf[2][2];
    #pragma unroll
    for (int t = 0; t < 2; ++t)
        #pragma unroll
        for (int s = 0; s < 2; ++s)
            qf[t][s] = *(const short8*)&q[(size_t)(qrowbase + t * 16 + l16) * 1024
                                          + h * 64 + s * 32 + g * 8];

    f32x4 O[2][4];
    #pragma unroll
    for (int t = 0; t < 2; ++t)
        #pragma unroll
        for (int d = 0; d < 4; ++d) O[t][d] = (f32x4)0.f;
    f32x4 Osum[2];
    Osum[0] = (f32x4)0.f; Osum[1] = (f32x4)0.f;
    float mrow[2] = {-1.0e4f, -1.0e4f};

    const float THR = 10.0f;  // defer-max threshold (log2 domain)

    short8 ones;
    #pragma unroll
    for (int e = 0; e < 8; ++e) ones[e] = (short)0x3F80;  // bf16 1.0

    // Staging geometry: chunk cid = w*128 + it*64 + lane; row = cid>>3, sub = cid&7.
    const int cid0 = w * 128 + lane;

    // ---- prologue: stage tile 0 (K + V via DMA) ----
    #pragma unroll
    for (int it = 0; it < 2; ++it) {
        int cid = cid0 + it * 64;
        int row = cid >> 3;
        int sub = cid & 7;
        int so  = (sub ^ (row & 7)) << 3;
        gload16(&k[kbase + (size_t)row * 1024 + so],
                (char*)&Ks[0][0] + w * 2048 + it * 1024);
        gload16(&vt[vtbase + (size_t)row * 2048 + so],
                (char*)&Vt[0][0] + w * 2048 + it * 1024);
    }
    __syncthreads();

    for (int kt = 0; kt < Ss / 64; ++kt) {
        const int cur = kt & 1;
        char* ksb = (char*)&Ks[cur][0];
        char* vtb = (char*)&Vt[cur][0];
        char* pbb = (char*)&Pb[w][0];

        // ---- prefetch tile kt+1 (K + V DMA into other buffer) ----
        if (kt + 1 < Ss / 64) {
            size_t knb = kbase + (size_t)(kt + 1) * 64 * 1024;
            size_t vnb = vtbase + (size_t)(kt + 1) * 64;
            #pragma unroll
            for (int it = 0; it < 2; ++it) {
                int cid = cid0 + it * 64;
                int row = cid >> 3;
                int sub = cid & 7;
                int so  = (sub ^ (row & 7)) << 3;
                gload16(&k[knb + (size_t)row * 1024 + so],
                        (char*)&Ks[cur ^ 1][0] + w * 2048 + it * 1024);
                gload16(&vt[vnb + (size_t)row * 2048 + so],
                        (char*)&Vt[cur ^ 1][0] + w * 2048 + it * 1024);
            }
        }

        // ---- S^T = K . Q^T : row = key (g*4+r), col = query (l16) ----
        f32x4 S[2][4];
        #pragma unroll
        for (int t = 0; t < 2; ++t)
            #pragma unroll
            for (int kt4 = 0; kt4 < 4; ++kt4) S[t][kt4] = (f32x4)0.f;
        #pragma unroll
        for (int kt4 = 0; kt4 < 4; ++kt4) {
            int key = kt4 * 16 + l16;
            short8 kf0 = *(const short8*)(ksb + key * 128 + ((g * 16) ^ sw));
            short8 kf1 = *(const short8*)(ksb + key * 128 + ((64 + g * 16) ^ sw));
            #pragma unroll
            for (int t = 0; t < 2; ++t) {
                S[t][kt4] = __builtin_amdgcn_mfma_f32_16x16x32_bf16(kf0, qf[t][0], S[t][kt4], 0, 0, 0);
                S[t][kt4] = __builtin_amdgcn_mfma_f32_16x16x32_bf16(kf1, qf[t][1], S[t][kt4], 0, 0, 0);
            }
        }

        // ---- mask ----
        int mk[4][4];
        #pragma unroll
        for (int kt4 = 0; kt4 < 4; ++kt4)
            *(int4*)&mk[kt4][0] = *(const int4*)&mask[bz * Ss + kt * 64 + kt4 * 16 + g * 4];
        #pragma unroll
        for (int t = 0; t < 2; ++t)
            #pragma unroll
            for (int kt4 = 0; kt4 < 4; ++kt4)
                #pragma unroll
                for (int r = 0; r < 4; ++r)
                    S[t][kt4][r] = mk[kt4][r] ? S[t][kt4][r] : -1e30f;

        // ---- row max per t: in-lane then across g ----
        float rm[2];
        #pragma unroll
        for (int t = 0; t < 2; ++t) {
            float m0 = fmaxf(fmaxf(S[t][0][0], S[t][0][1]), fmaxf(S[t][0][2], S[t][0][3]));
            float m1 = fmaxf(fmaxf(S[t][1][0], S[t][1][1]), fmaxf(S[t][1][2], S[t][1][3]));
            float m2 = fmaxf(fmaxf(S[t][2][0], S[t][2][1]), fmaxf(S[t][2][2], S[t][2][3]));
            float m3 = fmaxf(fmaxf(S[t][3][0], S[t][3][1]), fmaxf(S[t][3][2], S[t][3][3]));
            float m  = fmaxf(fmaxf(m0, m1), fmaxf(m2, m3));
            m = fmaxf(m, __shfl_xor(m, 16));
            m = fmaxf(m, __shfl_xor(m, 32));
            rm[t] = m;
        }

        // ---- defer-max rescale ----
        bool grow = (rm[0] > mrow[0] + THR) || (rm[1] > mrow[1] + THR);
        if (__any((int)grow)) {
            float mn0 = fmaxf(mrow[0], rm[0]);
            float mn1 = fmaxf(mrow[1], rm[1]);
            float rs0 = exp2f(mrow[0] - mn0);
            float rs1 = exp2f(mrow[1] - mn1);
            mrow[0] = mn0; mrow[1] = mn1;
            #pragma unroll
            for (int r = 0; r < 4; ++r) {
                float f0 = __shfl(rs0, g * 4 + r);   // S-layout -> O-layout
                float f1 = __shfl(rs1, g * 4 + r);
                #pragma unroll
                for (int dt = 0; dt < 4; ++dt) { O[0][dt][r] *= f0; O[1][dt][r] *= f1; }
                Osum[0][r] *= f0; Osum[1][r] *= f1;
            }
        }

        // ---- P = exp2(S - m), pack pairs, b64 write to per-wave LDS ----
        #pragma unroll
        for (int t = 0; t < 2; ++t) {
            int prow = t * 16 + l16;
            #pragma unroll
            for (int kt4 = 0; kt4 < 4; ++kt4) {
                float p0 = exp2f(S[t][kt4][0] - mrow[t]);
                float p1 = exp2f(S[t][kt4][1] - mrow[t]);
                float p2 = exp2f(S[t][kt4][2] - mrow[t]);
                float p3 = exp2f(S[t][kt4][3] - mrow[t]);
                unsigned int u01, u23;
                asm("v_cvt_pk_bf16_f32 %0, %1, %2" : "=v"(u01) : "v"(p0), "v"(p1));
                asm("v_cvt_pk_bf16_f32 %0, %1, %2" : "=v"(u23) : "v"(p2), "v"(p3));
                int pbyte = (kt4 * 32 + g * 8) ^ sw;
                *(uint2*)(pbb + prow * 128 + pbyte) = make_uint2(u01, u23);
            }
        }

        // ---- PV (+ ones column for row sums); vf shared across t ----
        #pragma unroll
        for (int ks = 0; ks < 2; ++ks) {
            short8 pf[2];
            #pragma unroll
            for (int t = 0; t < 2; ++t)
                pf[t] = *(const short8*)(pbb + (t * 16 + l16) * 128 + ((ks * 64 + g * 16) ^ sw));
            Osum[0] = __builtin_amdgcn_mfma_f32_16x16x32_bf16(pf[0], ones, Osum[0], 0, 0, 0);
            Osum[1] = __builtin_amdgcn_mfma_f32_16x16x32_bf16(pf[1], ones, Osum[1], 0, 0, 0);
            #pragma unroll
            for (int dt = 0; dt < 4; ++dt) {
                short8 vf = *(const short8*)(vtb + (dt * 16 + l16) * 128 + ((ks * 64 + g * 16) ^ sw));
                O[0][dt] = __builtin_amdgcn_mfma_f32_16x16x32_bf16(pf[0], vf, O[0][dt], 0, 0, 0);
                O[1][dt] = __builtin_amdgcn_mfma_f32_16x16x32_bf16(pf[1], vf, O[1][dt], 0, 0, 0);
            }
        }

        __syncthreads();   // drains K/V DMA (vmcnt) + orders buffer reuse
    }

    // ---- epilogue: normalize by Osum (already in O layout), store bf16 ----
    #pragma unroll
    for (int t = 0; t < 2; ++t)
        #pragma unroll
        for (int r = 0; r < 4; ++r) {
            float inv = 1.0f / Osum[t][r];
            int row = qrowbase + t * 16 + g * 4 + r;
            #pragma unroll
            for (int dt = 0; dt < 4; ++dt)
                ao[(size_t)row * 1024 + h * 64 + dt * 16 + l16] = f2bf(O[t][dt][r] * inv);
        }
}

extern "C" void kernel_launch(void* const* d_in, const int* in_sizes, int n_in,
                              void* d_out, int out_size, void* d_ws, size_t ws_size,
                              hipStream_t stream)
{
    const float* x  = (const float*)d_in[0];
    const int*   am = (const int*)d_in[1];
    const float* Wq = (const float*)d_in[2];
    const float* bq = (const float*)d_in[3];
    const float* Wk = (const float*)d_in[4];
    const float* bk = (const float*)d_in[5];
    const float* Wv = (const float*)d_in[6];
    const float* bv = (const float*)d_in[7];
    const float* Wo = (const float*)d_in[8];
    const float* bo = (const float*)d_in[9];
    float* out = (float*)d_out;

    const size_t NE = (size_t)Mm * Hh;           // 4M elems
    unsigned short* q    = (unsigned short*)d_ws;
    unsigned short* k    = q + NE;
    unsigned short* v    = k + NE;
    unsigned short* ao   = v + NE;
    unsigned short* xb   = ao + NE;
    unsigned short* wall = xb + NE;              // [Wq;Wk;Wv;Wo] rows
    unsigned short* wo   = wall + 3u * 1048576u;
    unsigned short* vtg  = wall + 4u * 1048576u; // transposed V

    convert_k<<<(2 * NE) / (256 * 8), 256, 0, stream>>>(x, Wq, Wk, Wv, Wo, xb, wall);
    gemm_qkv_k<<<dim3(Mm / 128, 3072 / 128), 256, 0, stream>>>(
        xb, wall, bq, bk, bv, q, k, v);
    rope_k<<<(Mm * 128) / 256, 256, 0, stream>>>(q, k);
    transpose_v_k<<<dim3(Ss / 64, Bb * NHh), 256, 0, stream>>>(v, vtg);
    flash_k<<<dim3(Ss / 128 * NHh * Bb), 256, 0, stream>>>(q, k, vtg, am, ao);
    gemm_out_k<<<dim3(Mm / 128, Hh / 128), 256, 0, stream>>>(ao, wo, bo, out);
}